// Round 9
// baseline (199.705 us; speedup 1.0000x reference)
//
#include <hip/hip_runtime.h>
#include <hip/hip_bf16.h>

typedef __bf16 bf16;
typedef __bf16 bf16x4 __attribute__((ext_vector_type(4)));
typedef __bf16 bf16x8 __attribute__((ext_vector_type(8)));
typedef float  f32x4 __attribute__((ext_vector_type(4)));

#define MFMA16(a, b, c) __builtin_amdgcn_mfma_f32_16x16x32_bf16((a), (b), (c), 0, 0, 0)

// async 16B/lane global->LDS (m97). LDS dst = uniform base + lane*16.
#define GLOBAL_LOAD_LDS16(gp, lp)                                                     \
    __builtin_amdgcn_global_load_lds(                                                 \
        (const __attribute__((address_space(1))) void*)(gp),                          \
        (__attribute__((address_space(3))) void*)(lp), 16, 0, 0)

// ---------------------------------------------------------------------------
// QKV projection v3: fp32 X/Wqkv consumed DIRECTLY (cvt fused in staging, no
// cvt2 dispatch). Register-prefetch staging (the attn-v6-proven pattern):
// next K-slab is loaded into static VGPRs during the MFMA phase, so the
// barrier sees a short cvt+ds_write burst instead of an exposed DMA drain.
// 128x128 tile, BK=32, LDS pitch 40 (spreads the 64B-row bank pattern).
//  QKPATH=true :  swapped MFMA -> qk[m][n] packed 8B along n.
//  QKPATH=false:  normal MFMA  -> vt[e][m] packed 8B along m.
template<bool QKPATH>
__device__ __forceinline__
void qkv_body(const float* __restrict__ A, const float* __restrict__ B,
              bf16* __restrict__ qk, bf16* __restrict__ vt,
              bf16* As, bf16* Bs, int m0, int n0)
{
    constexpr int M = 4096, PIT = 40;
    const int t = threadIdx.x;
    const int w = t >> 6, lane = t & 63, quad = lane >> 4, ln16 = lane & 15;
    const int wr = (w >> 1) * 64, wc = (w & 1) * 64;
    // staging: thread t -> row t>>1 (0..127), col-half (t&1)*16 of the 32-col slab
    const int strow = t >> 1;
    const int stc   = (t & 1) * 16;

    const float* Ap = A + (size_t)(m0 + strow) * 1024 + stc;
    const float* Bp = B + (size_t)(n0 + strow) * 1024 + stc;
    bf16* Adst = As + strow * PIT + stc;
    bf16* Bdst = Bs + strow * PIT + stc;

    // prefetch registers (STATIC indexing only -- R6 lesson)
    f32x4 ar[4], br[4];
#pragma unroll
    for (int u = 0; u < 4; u++) {
        ar[u] = *reinterpret_cast<const f32x4*>(Ap + u * 4);
        br[u] = *reinterpret_cast<const f32x4*>(Bp + u * 4);
    }

    f32x4 acc[4][4] = {};

    for (int k0 = 0; k0 < 1024; k0 += 32) {
        __syncthreads();  // readers of previous slab done
        // cvt regs -> LDS (16 bf16 per operand per thread, 2x ds_write_b128)
#pragma unroll
        for (int u = 0; u < 2; u++) {
            bf16x8 a8, b8;
#pragma unroll
            for (int v = 0; v < 4; v++) {
                a8[v] = (bf16)ar[2 * u][v];  a8[v + 4] = (bf16)ar[2 * u + 1][v];
                b8[v] = (bf16)br[2 * u][v];  b8[v + 4] = (bf16)br[2 * u + 1][v];
            }
            *reinterpret_cast<bf16x8*>(Adst + u * 8) = a8;
            *reinterpret_cast<bf16x8*>(Bdst + u * 8) = b8;
        }
        __syncthreads();

        if (k0 < 992) {  // prefetch next slab; lands during MFMA phase
#pragma unroll
            for (int u = 0; u < 4; u++) {
                ar[u] = *reinterpret_cast<const f32x4*>(Ap + k0 + 32 + u * 4);
                br[u] = *reinterpret_cast<const f32x4*>(Bp + k0 + 32 + u * 4);
            }
        }

        bf16x8 af[4];
#pragma unroll
        for (int mb = 0; mb < 4; mb++)
            af[mb] = *reinterpret_cast<const bf16x8*>(
                As + (wr + mb * 16 + ln16) * PIT + quad * 8);
#pragma unroll
        for (int nb = 0; nb < 4; nb++) {
            bf16x8 bv = *reinterpret_cast<const bf16x8*>(
                Bs + (wc + nb * 16 + ln16) * PIT + quad * 8);
#pragma unroll
            for (int mb = 0; mb < 4; mb++) {
                if constexpr (QKPATH) acc[mb][nb] = MFMA16(bv, af[mb], acc[mb][nb]);
                else                  acc[mb][nb] = MFMA16(af[mb], bv, acc[mb][nb]);
            }
        }
    }

    if constexpr (QKPATH) {
        // lane: m = ...+ln16 fixed, n = ...+quad*4 + r consecutive
#pragma unroll
        for (int mb = 0; mb < 4; mb++)
#pragma unroll
            for (int nb = 0; nb < 4; nb++) {
                size_t idx = (size_t)(m0 + wr + mb * 16 + ln16) * 2048
                           + (n0 + wc + nb * 16 + quad * 4);
                bf16x4 v;
#pragma unroll
                for (int r = 0; r < 4; r++) v[r] = (bf16)acc[mb][nb][r];
                *reinterpret_cast<bf16x4*>(&qk[idx]) = v;
            }
    } else {
        // lane: e(=n-2048) = ...+ln16 fixed, m = ...+quad*4 + r consecutive
#pragma unroll
        for (int mb = 0; mb < 4; mb++)
#pragma unroll
            for (int nb = 0; nb < 4; nb++) {
                const int e = n0 - 2048 + wc + nb * 16 + ln16;
                size_t idx = (size_t)e * M + (m0 + wr + mb * 16 + quad * 4);
                bf16x4 v;
#pragma unroll
                for (int r = 0; r < 4; r++) v[r] = (bf16)acc[mb][nb][r];
                *reinterpret_cast<bf16x4*>(&vt[idx]) = v;
            }
    }
}

__global__ __launch_bounds__(256)
void gemm_qkv(const float* __restrict__ X, const float* __restrict__ Wqkv,
              bf16* __restrict__ qk, bf16* __restrict__ vt)
{
    __shared__ __align__(16) bf16 As[128 * 40];  // 10 KB
    __shared__ __align__(16) bf16 Bs[128 * 40];  // 10 KB
    const int m0 = blockIdx.y * 128, n0 = blockIdx.x * 128;
    if (n0 < 2048) qkv_body<true >(X, Wqkv, qk, vt, As, Bs, m0, n0);
    else           qkv_body<false>(X, Wqkv, qk, vt, As, Bs, m0, n0);
}

// ---------------------------------------------------------------------------
// Out projection (R8, unchanged): z[M,K]*Wout[N,K]^T, Wout fp32 cvt in-staging.
// 128x64 tiles -> 512 blocks. A via stacked-halves global_load_lds.
__global__ __launch_bounds__(256)
void gemm_out(const bf16* __restrict__ A, const float* __restrict__ Wout,
              float* __restrict__ C)
{
    __shared__ __align__(16) bf16 As[8192];      // 2 halves x [128][32]
    __shared__ __align__(16) bf16 Bs[64 * 72];   // padded pitch 72

    const int t = threadIdx.x;
    const int w = t >> 6, lane = t & 63, quad = lane >> 4, ln16 = lane & 15;
    const int m0 = blockIdx.y * 128, n0 = blockIdx.x * 64;
    const int wr = (w >> 1) * 64, wc = (w & 1) * 32;
    const int srow = lane >> 2;
    const int scol = (lane & 3) * 8;
    const int brow = t >> 2, bc0 = (t & 3) * 16;

    f32x4 acc[4][2] = {};

    for (int k0 = 0; k0 < 1024; k0 += 64) {
        __syncthreads();
#pragma unroll
        for (int p = 0; p < 4; p++) {
            const int i = w * 4 + p;
            const int h = i >> 3, o = i & 7;
            GLOBAL_LOAD_LDS16(A + (size_t)(m0 + o * 16 + srow) * 1024 + k0 + h * 32 + scol,
                              As + h * 4096 + o * 512);
        }
        {
            const float* bp = Wout + (size_t)(n0 + brow) * 1024 + k0 + bc0;
            f32x4 b0 = *reinterpret_cast<const f32x4*>(bp);
            f32x4 b1 = *reinterpret_cast<const f32x4*>(bp + 4);
            f32x4 b2 = *reinterpret_cast<const f32x4*>(bp + 8);
            f32x4 b3 = *reinterpret_cast<const f32x4*>(bp + 12);
            bf16x8 r0, r1;
#pragma unroll
            for (int u = 0; u < 4; u++) {
                r0[u] = (bf16)b0[u]; r0[u + 4] = (bf16)b1[u];
                r1[u] = (bf16)b2[u]; r1[u + 4] = (bf16)b3[u];
            }
            *reinterpret_cast<bf16x8*>(&Bs[brow * 72 + bc0]) = r0;
            *reinterpret_cast<bf16x8*>(&Bs[brow * 72 + bc0 + 8]) = r1;
        }
        __syncthreads();

#pragma unroll
        for (int kki = 0; kki < 2; kki++) {
            bf16x8 af[4];
#pragma unroll
            for (int mb = 0; mb < 4; mb++)
                af[mb] = *reinterpret_cast<const bf16x8*>(
                    As + kki * 4096 + (wr + mb * 16 + ln16) * 32 + quad * 8);
#pragma unroll
            for (int nb = 0; nb < 2; nb++) {
                bf16x8 bv = *reinterpret_cast<const bf16x8*>(
                    &Bs[(wc + nb * 16 + ln16) * 72 + kki * 32 + quad * 8]);
#pragma unroll
                for (int mb = 0; mb < 4; mb++)
                    acc[mb][nb] = MFMA16(bv, af[mb], acc[mb][nb]);
            }
        }
    }

#pragma unroll
    for (int mb = 0; mb < 4; mb++)
#pragma unroll
        for (int nb = 0; nb < 2; nb++) {
            size_t idx = (size_t)(m0 + wr + mb * 16 + ln16) * 1024
                       + (n0 + wc + nb * 16 + quad * 4);
            *reinterpret_cast<f32x4*>(&C[idx]) = acc[mb][nb];
        }
}

// ---------------------------------------------------------------------------
// Fused causal flash attention v6 (R7, proven 47.4 us) — unchanged.
__global__ __launch_bounds__(256)
void attn_flash6(const bf16* __restrict__ qk, const bf16* __restrict__ vt,
                 bf16* __restrict__ z)
{
    constexpr int Tn = 2048, Dm = 1024, QLD = 2048, VLD = 4096;
    constexpr int KP = 72;
    __shared__ __align__(16) bf16 Ks[64 * KP];
    __shared__ __align__(16) bf16 VTs[64 * KP];
    __shared__ __align__(16) bf16 Ps[64 * KP];

    const int t = threadIdx.x;
    const int w = t >> 6, lane = t & 63, quad = lane >> 4, ln16 = lane & 15;
    const int q = blockIdx.x >> 5, g = blockIdx.x & 31;
    const int s4 = q >> 3, q0i = q & 7;
    const int j = (s4 == 0) ? q0i : (s4 == 1) ? (15 - q0i)
                : (s4 == 2) ? (16 + q0i) : (31 - q0i);
    const int b = g >> 4, h = g & 15;
    const int q0 = j * 64;

    const bf16* Qb = qk + (size_t)b * Tn * QLD + h * 64;
    const bf16* Kb = Qb + 1024;
    const bf16* Vb = vt + (size_t)(h * 64) * VLD + b * Tn;

    constexpr float C2 = 0.125f * 1.44269504089f;
    bf16x8 qf[2];
#pragma unroll
    for (int kki = 0; kki < 2; kki++) {
        bf16x8 qv = *reinterpret_cast<const bf16x8*>(
            Qb + (size_t)(q0 + w * 16 + ln16) * QLD + kki * 32 + quad * 8);
#pragma unroll
        for (int u = 0; u < 8; u++) qf[kki][u] = (bf16)((float)qv[u] * C2);
    }

    bf16x8 vones;
#pragma unroll
    for (int u = 0; u < 8; u++) vones[u] = (bf16)1.0f;

    const int sr = t >> 3;
    const int sseg = (t & 7) * 8;

    bf16x8 kreg[2], vreg[2];
#pragma unroll
    for (int p = 0; p < 2; p++) {
        kreg[p] = *reinterpret_cast<const bf16x8*>(Kb + (size_t)(sr + p * 32) * QLD + sseg);
        vreg[p] = *reinterpret_cast<const bf16x8*>(Vb + (size_t)(sr + p * 32) * VLD + sseg);
    }

    f32x4 accO[5] = {};
    const int qloc = w * 16 + ln16;

    for (int kt = 0; kt <= j; kt++) {
        __syncthreads();
#pragma unroll
        for (int p = 0; p < 2; p++) {
            *reinterpret_cast<bf16x8*>(&Ks[(sr + p * 32) * KP + sseg]) = kreg[p];
            *reinterpret_cast<bf16x8*>(&VTs[(sr + p * 32) * KP + sseg]) = vreg[p];
        }
        __syncthreads();

        if (kt < j) {
            const int k1 = (kt + 1) * 64;
#pragma unroll
            for (int p = 0; p < 2; p++) {
                kreg[p] = *reinterpret_cast<const bf16x8*>(
                    Kb + (size_t)(k1 + sr + p * 32) * QLD + sseg);
                vreg[p] = *reinterpret_cast<const bf16x8*>(
                    Vb + (size_t)(sr + p * 32) * VLD + k1 + sseg);
            }
        }

        f32x4 aS[4] = {};
#pragma unroll
        for (int kki = 0; kki < 2; kki++)
#pragma unroll
            for (int nb = 0; nb < 4; nb++) {
                bf16x8 kb = *reinterpret_cast<const bf16x8*>(
                    &Ks[(nb * 16 + ln16) * KP + kki * 32 + quad * 8]);
                aS[nb] = MFMA16(kb, qf[kki], aS[nb]);
            }

        if (kt == j) {
#pragma unroll
            for (int nb = 0; nb < 4; nb++) {
                bf16x4 pv;
#pragma unroll
                for (int r = 0; r < 4; r++) {
                    float p = __builtin_amdgcn_exp2f(aS[nb][r]);
                    if ((nb * 16 + quad * 4 + r) > qloc) p = 0.f;
                    pv[r] = (bf16)p;
                }
                *reinterpret_cast<bf16x4*>(&Ps[qloc * KP + nb * 16 + quad * 4]) = pv;
            }
        } else {
#pragma unroll
            for (int nb = 0; nb < 4; nb++) {
                bf16x4 pv;
#pragma unroll
                for (int r = 0; r < 4; r++)
                    pv[r] = (bf16)__builtin_amdgcn_exp2f(aS[nb][r]);
                *reinterpret_cast<bf16x4*>(&Ps[qloc * KP + nb * 16 + quad * 4]) = pv;
            }
        }
        asm volatile("s_waitcnt lgkmcnt(0)" ::: "memory");

#pragma unroll
        for (int kki = 0; kki < 2; kki++) {
            bf16x8 pa = *reinterpret_cast<const bf16x8*>(
                &Ps[qloc * KP + kki * 32 + quad * 8]);
#pragma unroll
            for (int nb = 0; nb < 4; nb++) {
                bf16x8 vb = *reinterpret_cast<const bf16x8*>(
                    &VTs[(nb * 16 + ln16) * KP + kki * 32 + quad * 8]);
                accO[nb] = MFMA16(vb, pa, accO[nb]);
            }
            accO[4] = MFMA16(vones, pa, accO[4]);
        }
    }

    const float linv = 1.0f / accO[4][0];
    const size_t zr = ((size_t)b * Tn + q0 + qloc) * Dm + h * 64;
#pragma unroll
    for (int nb = 0; nb < 4; nb++) {
        bf16x4 v;
#pragma unroll
        for (int r = 0; r < 4; r++) v[r] = (bf16)(accO[nb][r] * linv);
        *reinterpret_cast<bf16x4*>(z + zr + nb * 16 + quad * 4) = v;
    }
}

// ---------------------------------------------------------------------------
extern "C" void kernel_launch(void* const* d_in, const int* in_sizes, int n_in,
                              void* d_out, int out_size, void* d_ws, size_t ws_size,
                              hipStream_t stream)
{
    constexpr int B = 2, T = 2048, D = 1024;
    constexpr int M = B * T;  // 4096

    const float* X    = (const float*)d_in[0];
    const float* Wqkv = (const float*)d_in[1];
    const float* Wout = (const float*)d_in[2];
    float* out = (float*)d_out;

    // ws: qk [M][2048] 16 MiB | vt [1024][M] 8 MiB | z [M][1024] 8 MiB
    bf16* qk  = (bf16*)d_ws;
    bf16* vt  = qk + (size_t)M * 2048;
    bf16* zbf = vt + (size_t)1024 * M;

    dim3 blk(256);
    // fp32 inputs consumed directly -- no conversion dispatches, 3 kernels total
    gemm_qkv<<<dim3(24, 32), blk, 0, stream>>>(X, Wqkv, qk, vt);
    attn_flash6<<<dim3(1024), blk, 0, stream>>>(qk, vt, zbf);
    gemm_out<<<dim3(16, 32), blk, 0, stream>>>(zbf, Wout, out);
}

// Round 10
// 181.954 us; speedup vs baseline: 1.0976x; 1.0976x over previous
//
#include <hip/hip_runtime.h>
#include <hip/hip_bf16.h>

typedef __bf16 bf16;
typedef __bf16 bf16x4 __attribute__((ext_vector_type(4)));
typedef __bf16 bf16x8 __attribute__((ext_vector_type(8)));
typedef float  f32x4 __attribute__((ext_vector_type(4)));

#define MFMA16(a, b, c) __builtin_amdgcn_mfma_f32_16x16x32_bf16((a), (b), (c), 0, 0, 0)

// async 16B/lane global->LDS (m97). LDS dst = uniform base + lane*16.
#define GLOBAL_LOAD_LDS16(gp, lp)                                                     \
    __builtin_amdgcn_global_load_lds(                                                 \
        (const __attribute__((address_space(1))) void*)(gp),                          \
        (__attribute__((address_space(3))) void*)(lp), 16, 0, 0)

// ---------------------------------------------------------------------------
// fp32 -> bf16, two sources into one contiguous dst (8 elems/thread)
__global__ __launch_bounds__(256)
void cvt2(const float* __restrict__ s1, const float* __restrict__ s2,
          bf16* __restrict__ dst, int n1, int ntot)
{
    int i = blockIdx.x * 256 + threadIdx.x;
    if (i >= ntot) return;
    const float* s = (i < n1) ? s1 + (size_t)i * 8 : s2 + (size_t)(i - n1) * 8;
    f32x4 a = *reinterpret_cast<const f32x4*>(s);
    f32x4 b = *reinterpret_cast<const f32x4*>(s + 4);
    bf16x8 r;
#pragma unroll
    for (int u = 0; u < 4; u++) { r[u] = (bf16)a[u]; r[u + 4] = (bf16)b[u]; }
    *reinterpret_cast<bf16x8*>(dst + (size_t)i * 8) = r;
}

// ---------------------------------------------------------------------------
// QKV projection (R8-proven, 48.9 us): bf16 inputs, BK=64 via two stacked
// 32-col halves, global_load_lds DMA staging, 128x128 tiles, 768 blocks.
//  QKPATH=true  (n0<2048):  swapped MFMA -> qk[m][n] packed 8B along n.
//  QKPATH=false (V blocks): normal MFMA  -> vt[e][m] packed 8B along m.
template<bool QKPATH>
__device__ __forceinline__
void qkv_body(const bf16* __restrict__ A, const bf16* __restrict__ B,
              bf16* __restrict__ qk, bf16* __restrict__ vt,
              bf16* As, bf16* Bs, int m0, int n0)
{
    constexpr int M = 4096;
    const int t = threadIdx.x;
    const int w = t >> 6, lane = t & 63, quad = lane >> 4, ln16 = lane & 15;
    const int wr = (w >> 1) * 64, wc = (w & 1) * 64;
    const int srow = lane >> 2;
    const int scol = (lane & 3) * 8;

    f32x4 acc[4][4] = {};

    for (int k0 = 0; k0 < 1024; k0 += 64) {
        __syncthreads();
#pragma unroll
        for (int p = 0; p < 4; p++) {
            const int i = w * 4 + p;      // 16 ops: h = k-half, o = 16-row group
            const int h = i >> 3, o = i & 7;
            GLOBAL_LOAD_LDS16(A + (size_t)(m0 + o * 16 + srow) * 1024 + k0 + h * 32 + scol,
                              As + h * 4096 + o * 512);
            GLOBAL_LOAD_LDS16(B + (size_t)(n0 + o * 16 + srow) * 1024 + k0 + h * 32 + scol,
                              Bs + h * 4096 + o * 512);
        }
        __syncthreads();

#pragma unroll
        for (int kki = 0; kki < 2; kki++) {
            bf16x8 af[4];
#pragma unroll
            for (int mb = 0; mb < 4; mb++)
                af[mb] = *reinterpret_cast<const bf16x8*>(
                    As + kki * 4096 + (wr + mb * 16 + ln16) * 32 + quad * 8);
#pragma unroll
            for (int nb = 0; nb < 4; nb++) {
                bf16x8 bv = *reinterpret_cast<const bf16x8*>(
                    Bs + kki * 4096 + (wc + nb * 16 + ln16) * 32 + quad * 8);
#pragma unroll
                for (int mb = 0; mb < 4; mb++) {
                    if constexpr (QKPATH) acc[mb][nb] = MFMA16(bv, af[mb], acc[mb][nb]);
                    else                  acc[mb][nb] = MFMA16(af[mb], bv, acc[mb][nb]);
                }
            }
        }
    }

    if constexpr (QKPATH) {
#pragma unroll
        for (int mb = 0; mb < 4; mb++)
#pragma unroll
            for (int nb = 0; nb < 4; nb++) {
                size_t idx = (size_t)(m0 + wr + mb * 16 + ln16) * 2048
                           + (n0 + wc + nb * 16 + quad * 4);
                bf16x4 v;
#pragma unroll
                for (int r = 0; r < 4; r++) v[r] = (bf16)acc[mb][nb][r];
                *reinterpret_cast<bf16x4*>(&qk[idx]) = v;
            }
    } else {
#pragma unroll
        for (int mb = 0; mb < 4; mb++)
#pragma unroll
            for (int nb = 0; nb < 4; nb++) {
                const int e = n0 - 2048 + wc + nb * 16 + ln16;
                size_t idx = (size_t)e * M + (m0 + wr + mb * 16 + quad * 4);
                bf16x4 v;
#pragma unroll
                for (int r = 0; r < 4; r++) v[r] = (bf16)acc[mb][nb][r];
                *reinterpret_cast<bf16x4*>(&vt[idx]) = v;
            }
    }
}

__global__ __launch_bounds__(256)
void gemm_qkv(const bf16* __restrict__ A, const bf16* __restrict__ B,
              bf16* __restrict__ qk, bf16* __restrict__ vt)
{
    __shared__ __align__(16) bf16 As[8192];  // 2 halves x [128][32]
    __shared__ __align__(16) bf16 Bs[8192];
    const int m0 = blockIdx.y * 128, n0 = blockIdx.x * 128;
    if (n0 < 2048) qkv_body<true >(A, B, qk, vt, As, Bs, m0, n0);
    else           qkv_body<false>(A, B, qk, vt, As, Bs, m0, n0);
}

// ---------------------------------------------------------------------------
// Out projection v3: all-bf16 DMA staging (NO in-phase load-use chain), 64x64
// tiles -> 1024 blocks (4/CU: the occupancy regime that made attn v6 and
// gemm_qkv work; R3-R9's 1-2 blocks/CU versions were latency-exposed ~60 us).
// BK=64 as two stacked halves. Swapped MFMA -> packed f32x4 C-stores.
__global__ __launch_bounds__(256)
void gemm_out(const bf16* __restrict__ A, const bf16* __restrict__ Bw,
              float* __restrict__ C)
{
    __shared__ __align__(16) bf16 As[4096];  // 2 halves x [64][32]
    __shared__ __align__(16) bf16 Bs[4096];

    const int t = threadIdx.x;
    const int w = t >> 6, lane = t & 63, quad = lane >> 4, ln16 = lane & 15;
    const int m0 = blockIdx.y * 64, n0 = blockIdx.x * 64;
    const int wr = (w >> 1) * 32, wc = (w & 1) * 32;
    const int srow = lane >> 2;
    const int scol = (lane & 3) * 8;

    f32x4 acc[2][2] = {};

    for (int k0 = 0; k0 < 1024; k0 += 64) {
        __syncthreads();
#pragma unroll
        for (int p = 0; p < 2; p++) {
            const int i = w * 2 + p;          // 8 ops each for A and B
            const int h = i >> 2, o = i & 3;  // k-half, 16-row group
            GLOBAL_LOAD_LDS16(A  + (size_t)(m0 + o * 16 + srow) * 1024 + k0 + h * 32 + scol,
                              As + h * 2048 + o * 512);
            GLOBAL_LOAD_LDS16(Bw + (size_t)(n0 + o * 16 + srow) * 1024 + k0 + h * 32 + scol,
                              Bs + h * 2048 + o * 512);
        }
        __syncthreads();

#pragma unroll
        for (int kki = 0; kki < 2; kki++) {
            bf16x8 af[2];
#pragma unroll
            for (int mb = 0; mb < 2; mb++)
                af[mb] = *reinterpret_cast<const bf16x8*>(
                    As + kki * 2048 + (wr + mb * 16 + ln16) * 32 + quad * 8);
#pragma unroll
            for (int nb = 0; nb < 2; nb++) {
                bf16x8 bv = *reinterpret_cast<const bf16x8*>(
                    Bs + kki * 2048 + (wc + nb * 16 + ln16) * 32 + quad * 8);
#pragma unroll
                for (int mb = 0; mb < 2; mb++)
                    acc[mb][nb] = MFMA16(bv, af[mb], acc[mb][nb]);  // swapped
            }
        }
    }

    // lane: m = ...+ln16 fixed, n = ...+quad*4 + r -> packed f32x4 stores
#pragma unroll
    for (int mb = 0; mb < 2; mb++)
#pragma unroll
        for (int nb = 0; nb < 2; nb++) {
            size_t idx = (size_t)(m0 + wr + mb * 16 + ln16) * 1024
                       + (n0 + wc + nb * 16 + quad * 4);
            *reinterpret_cast<f32x4*>(&C[idx]) = acc[mb][nb];
        }
}

// ---------------------------------------------------------------------------
// Fused causal flash attention v6 (R7, proven 47.4 us) — unchanged.
__global__ __launch_bounds__(256)
void attn_flash6(const bf16* __restrict__ qk, const bf16* __restrict__ vt,
                 bf16* __restrict__ z)
{
    constexpr int Tn = 2048, Dm = 1024, QLD = 2048, VLD = 4096;
    constexpr int KP = 72;
    __shared__ __align__(16) bf16 Ks[64 * KP];
    __shared__ __align__(16) bf16 VTs[64 * KP];
    __shared__ __align__(16) bf16 Ps[64 * KP];

    const int t = threadIdx.x;
    const int w = t >> 6, lane = t & 63, quad = lane >> 4, ln16 = lane & 15;
    const int q = blockIdx.x >> 5, g = blockIdx.x & 31;
    const int s4 = q >> 3, q0i = q & 7;
    const int j = (s4 == 0) ? q0i : (s4 == 1) ? (15 - q0i)
                : (s4 == 2) ? (16 + q0i) : (31 - q0i);
    const int b = g >> 4, h = g & 15;
    const int q0 = j * 64;

    const bf16* Qb = qk + (size_t)b * Tn * QLD + h * 64;
    const bf16* Kb = Qb + 1024;
    const bf16* Vb = vt + (size_t)(h * 64) * VLD + b * Tn;

    constexpr float C2 = 0.125f * 1.44269504089f;
    bf16x8 qf[2];
#pragma unroll
    for (int kki = 0; kki < 2; kki++) {
        bf16x8 qv = *reinterpret_cast<const bf16x8*>(
            Qb + (size_t)(q0 + w * 16 + ln16) * QLD + kki * 32 + quad * 8);
#pragma unroll
        for (int u = 0; u < 8; u++) qf[kki][u] = (bf16)((float)qv[u] * C2);
    }

    bf16x8 vones;
#pragma unroll
    for (int u = 0; u < 8; u++) vones[u] = (bf16)1.0f;

    const int sr = t >> 3;
    const int sseg = (t & 7) * 8;

    bf16x8 kreg[2], vreg[2];
#pragma unroll
    for (int p = 0; p < 2; p++) {
        kreg[p] = *reinterpret_cast<const bf16x8*>(Kb + (size_t)(sr + p * 32) * QLD + sseg);
        vreg[p] = *reinterpret_cast<const bf16x8*>(Vb + (size_t)(sr + p * 32) * VLD + sseg);
    }

    f32x4 accO[5] = {};
    const int qloc = w * 16 + ln16;

    for (int kt = 0; kt <= j; kt++) {
        __syncthreads();
#pragma unroll
        for (int p = 0; p < 2; p++) {
            *reinterpret_cast<bf16x8*>(&Ks[(sr + p * 32) * KP + sseg]) = kreg[p];
            *reinterpret_cast<bf16x8*>(&VTs[(sr + p * 32) * KP + sseg]) = vreg[p];
        }
        __syncthreads();

        if (kt < j) {
            const int k1 = (kt + 1) * 64;
#pragma unroll
            for (int p = 0; p < 2; p++) {
                kreg[p] = *reinterpret_cast<const bf16x8*>(
                    Kb + (size_t)(k1 + sr + p * 32) * QLD + sseg);
                vreg[p] = *reinterpret_cast<const bf16x8*>(
                    Vb + (size_t)(sr + p * 32) * VLD + k1 + sseg);
            }
        }

        f32x4 aS[4] = {};
#pragma unroll
        for (int kki = 0; kki < 2; kki++)
#pragma unroll
            for (int nb = 0; nb < 4; nb++) {
                bf16x8 kb = *reinterpret_cast<const bf16x8*>(
                    &Ks[(nb * 16 + ln16) * KP + kki * 32 + quad * 8]);
                aS[nb] = MFMA16(kb, qf[kki], aS[nb]);
            }

        if (kt == j) {
#pragma unroll
            for (int nb = 0; nb < 4; nb++) {
                bf16x4 pv;
#pragma unroll
                for (int r = 0; r < 4; r++) {
                    float p = __builtin_amdgcn_exp2f(aS[nb][r]);
                    if ((nb * 16 + quad * 4 + r) > qloc) p = 0.f;
                    pv[r] = (bf16)p;
                }
                *reinterpret_cast<bf16x4*>(&Ps[qloc * KP + nb * 16 + quad * 4]) = pv;
            }
        } else {
#pragma unroll
            for (int nb = 0; nb < 4; nb++) {
                bf16x4 pv;
#pragma unroll
                for (int r = 0; r < 4; r++)
                    pv[r] = (bf16)__builtin_amdgcn_exp2f(aS[nb][r]);
                *reinterpret_cast<bf16x4*>(&Ps[qloc * KP + nb * 16 + quad * 4]) = pv;
            }
        }
        asm volatile("s_waitcnt lgkmcnt(0)" ::: "memory");

#pragma unroll
        for (int kki = 0; kki < 2; kki++) {
            bf16x8 pa = *reinterpret_cast<const bf16x8*>(
                &Ps[qloc * KP + kki * 32 + quad * 8]);
#pragma unroll
            for (int nb = 0; nb < 4; nb++) {
                bf16x8 vb = *reinterpret_cast<const bf16x8*>(
                    &VTs[(nb * 16 + ln16) * KP + kki * 32 + quad * 8]);
                accO[nb] = MFMA16(vb, pa, accO[nb]);
            }
            accO[4] = MFMA16(vones, pa, accO[4]);
        }
    }

    const float linv = 1.0f / accO[4][0];
    const size_t zr = ((size_t)b * Tn + q0 + qloc) * Dm + h * 64;
#pragma unroll
    for (int nb = 0; nb < 4; nb++) {
        bf16x4 v;
#pragma unroll
        for (int r = 0; r < 4; r++) v[r] = (bf16)(accO[nb][r] * linv);
        *reinterpret_cast<bf16x4*>(z + zr + nb * 16 + quad * 4) = v;
    }
}

// ---------------------------------------------------------------------------
extern "C" void kernel_launch(void* const* d_in, const int* in_sizes, int n_in,
                              void* d_out, int out_size, void* d_ws, size_t ws_size,
                              hipStream_t stream)
{
    constexpr int B = 2, T = 2048, D = 1024;
    constexpr int M = B * T;  // 4096

    const float* X    = (const float*)d_in[0];
    const float* Wqkv = (const float*)d_in[1];
    const float* Wout = (const float*)d_in[2];
    float* out = (float*)d_out;

    // ws: qk [M][2048] 16 MiB | vt [1024][M] 8 MiB | z [M][1024] 8 MiB
    bf16* qk  = (bf16*)d_ws;
    bf16* vt  = qk + (size_t)M * 2048;
    bf16* zbf = vt + (size_t)1024 * M;
    // d_out as scratch until gemm_out writes it (Xbf 8 MiB + Wqkvbf 6 MiB <= 16)
    bf16* Xbf    = (bf16*)d_out;
    bf16* Wqkvbf = Xbf + (size_t)M * D;
    // Woutbf reuses the vt region -- vt is dead after attn_flash6
    bf16* Woutbf = vt;

    dim3 blk(256);
    const int n1 = M * D / 8, n2 = 3 * D * D / 8;
    cvt2<<<(n1 + n2 + 255) / 256, blk, 0, stream>>>(X, Wqkv, Xbf, n1, n1 + n2);

    gemm_qkv<<<dim3(24, 32), blk, 0, stream>>>(Xbf, Wqkvbf, qk, vt);

    attn_flash6<<<dim3(1024), blk, 0, stream>>>(qk, vt, zbf);

    const int n3 = D * D / 8;
    cvt2<<<(n3 + 255) / 256, blk, 0, stream>>>(Wout, Wout, Woutbf, n3, n3);

    gemm_out<<<dim3(16, 64), blk, 0, stream>>>(zbf, Woutbf, out);
}